// Round 7
// baseline (182.621 us; speedup 1.0000x reference)
//
#include <hip/hip_runtime.h>
#include <hip/hip_bf16.h>
#include <stdint.h>

#define B_ 2
#define S_ 2048
#define D_ 1024
#define H_ 16
#define HD_ 64
#define KJL 32
#define N3 3072
#define N2 2048

typedef __attribute__((ext_vector_type(8))) __bf16 bf16x8;
typedef __attribute__((ext_vector_type(4))) float floatx4;
typedef __attribute__((ext_vector_type(4))) short short4v;
typedef __attribute__((ext_vector_type(2))) unsigned int uint2v;

__device__ __forceinline__ unsigned short f2b(float x) {
  union { float f; unsigned u; } v; v.f = x;
  unsigned r = v.u + 0x7fffu + ((v.u >> 16) & 1u);
  return (unsigned short)(r >> 16);
}

// pack two floats to packed bf16 (round via +0x8000): hi<<16 | lo
__device__ __forceinline__ unsigned int pkbf(float lo, float hi) {
  union { float f; unsigned u; } a, b;
  a.f = lo; b.f = hi;
  return __builtin_amdgcn_perm(b.u + 0x8000u, a.u + 0x8000u, 0x07060302u);
}

__device__ __forceinline__ void async16(const void* g, void* l) {
  __builtin_amdgcn_global_load_lds((__attribute__((address_space(1))) void*)(g),
                                   (__attribute__((address_space(3))) void*)(l),
                                   16, 0, 0);
}

// ---------------- fused prep: cvt4 | tcvt(V cols) | tcvt(W_proj) | wjl ----------------
__global__ __launch_bounds__(256)
void prep_kernel(const float* __restrict__ hidden, unsigned short* __restrict__ hB,
                 const float* __restrict__ W_attn, const float* __restrict__ b_attn,
                 const float* __restrict__ Sp, const float* __restrict__ W_proj,
                 unsigned short* __restrict__ Bt2, unsigned short* __restrict__ WpT,
                 float* __restrict__ bias2) {
  __shared__ float shmem[2048];
  const int bid = blockIdx.x;
  const int tid = threadIdx.x;

  if (bid < 512) {                      // ---- cvt4: hidden -> hB ----
    const int n4 = (B_ * S_ * D_) / 4;
    int i = bid * 256 + tid;
    for (; i < n4; i += 512 * 256) {
      float4 v = *(const float4*)(hidden + 4 * (size_t)i);
      short4v o = {(short)f2b(v.x), (short)f2b(v.y), (short)f2b(v.z), (short)f2b(v.w)};
      *(short4v*)(hB + 4 * (size_t)i) = o;
    }
  } else if (bid < 2560) {              // ---- tcvt: 32x32 transpose-convert tiles ----
    const float* in;
    unsigned short* out;
    int Cs, local;
    if (bid < 1536) { local = bid - 512;  in = W_attn + 2048; out = Bt2 + 1024 * 1024; Cs = N3; }
    else            { local = bid - 1536; in = W_proj;        out = WpT;               Cs = D_; }
    float (*t)[33] = (float(*)[33])shmem;
    int c0 = (local & 31) * 32, r0 = (local >> 5) * 32;
    int tx = tid & 31, ty = tid >> 5;
    for (int j = 0; j < 32; j += 8)
      t[ty + j][tx] = in[(size_t)(r0 + ty + j) * Cs + c0 + tx];
    __syncthreads();
    for (int j = 0; j < 32; j += 8)
      out[(size_t)(c0 + ty + j) * D_ + r0 + tx] = f2b(t[tx][ty + j]);
  } else {                              // ---- wjl: fused JL weights ----
    const int lb = bid - 2560;          // 0..127
    const int part = lb >> 6;           // 0 = Q, 1 = K
    const int h = (lb >> 2) & 15;
    const int dc = lb & 3;
    for (int i = tid; i < 32 * 64; i += 256) shmem[i] = Sp[i];
    __syncthreads();
    const float scale = part ? 1.0f : 0.125f * 1.44269504f;
    const int d = dc * 256 + tid;
    float w[64];
    const float* src = W_attn + (size_t)d * N3 + part * D_ + h * 64;
    for (int j = 0; j < 16; ++j) {
      float4 v = *(const float4*)&src[j * 4];
      w[j * 4 + 0] = v.x; w[j * 4 + 1] = v.y; w[j * 4 + 2] = v.z; w[j * 4 + 3] = v.w;
    }
    const int nbase = part * 512 + h * 32;
    for (int kjl = 0; kjl < 32; ++kjl) {
      float acc = 0.f;
      for (int hd = 0; hd < 64; ++hd) acc += w[hd] * shmem[kjl * 64 + hd];
      Bt2[(size_t)(nbase + kjl) * D_ + d] = f2b(acc * scale);
    }
    if (dc == 0 && tid < 32) {
      float acc = 0.f;
      for (int hd = 0; hd < 64; ++hd) acc += b_attn[part * D_ + h * 64 + hd] * shmem[tid * 64 + hd];
      bias2[nbase + tid] = acc * scale;
    }
  }
}

// ---------------- fused qkv+JL GEMM: 128x128 tiles, BK=64 ----------------
__global__ __launch_bounds__(256, 2)
void qkv2_gemm_kernel(const unsigned short* __restrict__ A,
                      const unsigned short* __restrict__ Bt,
                      const float* __restrict__ b_attn,
                      const float* __restrict__ bias2,
                      unsigned short* __restrict__ Qjl,
                      unsigned short* __restrict__ Kjl,
                      unsigned short* __restrict__ Vc) {
  __shared__ __align__(16) unsigned short As[2][128 * 32];
  __shared__ __align__(16) unsigned short Bs[2][128 * 32];
  const int tid = threadIdx.x;
  const int lane = tid & 63, wv = tid >> 6;
  const int quad = lane >> 4, col = lane & 15;
  const int wm = wv >> 1, wn = wv & 1;
  const int m0 = blockIdx.y * 128, n0 = blockIdx.x * 128;

  floatx4 acc[4][4] = {};

  for (int kk = 0; kk < D_; kk += 64) {
    for (int it = 0; it < 4; ++it) {
      int c = it * 256 + tid;            // 0..1023
      int ks = c >> 9, row = (c >> 2) & 127, kc = c & 3;
      async16(A + (size_t)(m0 + row) * D_ + kk + ks * 32 + kc * 8,
              (unsigned short*)As + c * 8);
    }
    for (int it = 0; it < 4; ++it) {
      int c = it * 256 + tid;
      int ks = c >> 9, row = (c >> 2) & 127, kc = c & 3;
      async16(Bt + (size_t)(n0 + row) * D_ + kk + ks * 32 + kc * 8,
              (unsigned short*)Bs + c * 8);
    }
    asm volatile("s_waitcnt vmcnt(0)" ::: "memory");
    __syncthreads();
    for (int ks = 0; ks < 2; ++ks) {
      bf16x8 af[4], bfr[4];
      for (int mt = 0; mt < 4; ++mt)
        af[mt] = *(const bf16x8*)&As[ks][(wm * 64 + mt * 16 + col) * 32 + quad * 8];
      for (int nt = 0; nt < 4; ++nt)
        bfr[nt] = *(const bf16x8*)&Bs[ks][(wn * 64 + nt * 16 + col) * 32 + quad * 8];
      for (int mt = 0; mt < 4; ++mt)
        for (int nt = 0; nt < 4; ++nt)
          acc[mt][nt] = __builtin_amdgcn_mfma_f32_16x16x32_bf16(
              af[mt], bfr[nt], acc[mt][nt], 0, 0, 0);
    }
    __syncthreads();
  }

  const int pq = n0 >> 9;  // 0=Q, 1=K, >=2 -> V
  for (int mt = 0; mt < 4; ++mt) {
    int gm0 = m0 + wm * 64 + mt * 16 + quad * 4;
    int b = gm0 >> 11, s = gm0 & (S_ - 1);
    for (int nt = 0; nt < 4; ++nt) {
      int gn = n0 + wn * 64 + nt * 16 + col;
      if (pq >= 2) {
        int vcol = gn - 1024;
        float bs = b_attn[2048 + vcol];
        int h = vcol >> 6, hd = vcol & 63;
        short4v vv;
        for (int i = 0; i < 4; ++i)
          vv[i] = (short)f2b(acc[mt][nt][i] + bs);
        size_t idx = ((((size_t)(b * H_ + h) * 64 + (s >> 5)) * 64 + hd) * 32 + (s & 31));
        *(short4v*)&Vc[idx] = vv;
      } else {
        float bs = bias2[gn];
        int gl = gn & 511;
        int h = gl >> 5, kjl = gl & 31;
        unsigned short* dst = pq ? Kjl : Qjl;
        size_t base = ((size_t)(b * H_ + h) * S_ + s) * KJL + kjl;
        for (int i = 0; i < 4; ++i)
          dst[base + (size_t)i * KJL] = f2b(acc[mt][nt][i] + bs);
      }
    }
  }
}

// ---------------- two-phase uniform flash attention: 17 chunks/block BY CONSTRUCTION ----------------
// Grid 256 = 32 bh x 8 u; block u runs tile-group g=u, then g=15-u SEQUENTIALLY.
// Every block = (u+1)+(16-u) = 17 chunks exactly -> zero inter-block imbalance, NO
// co-residency/dispatch assumptions (the round-14/15 (g,15-g) pairing was a gamble;
// all attn variants plateaued 43-47us consistent with it failing: worst CU ran 2
// heavy blocks ~32 chunk-times). 1 block/CU (LDS 104KB).
// Pipeline: K/V TRIPLE-buffered, staged 2 chunks ahead via global_load_lds; loop uses
// COUNTED s_waitcnt vmcnt(6) + raw s_barrier -- NEVER __syncthreads() (its implicit
// vmcnt(0) drain before s_barrier killed the prefetch every chunk = the m97-ceiling
// mechanism; counted-vmcnt is the +38-73% T4 lever).
// LESSONS ENCODED:
//  * Round 13: register K/V prefetch spills (WRITE_SIZE 96MB) -- stage through LDS.
//  * Round 16: P-strip halving added serial lgkm waits per chunk -- full 8KB strips.
//  * Round 11: never fence/merge through global in-kernel (~170us cross-XCD stalls).
//  * Round 8: don't cap launch_bounds min-waves. Round 5: no runtime-indexed reg arrays.
__global__ __launch_bounds__(256, 1)
void attn_kernel(const unsigned short* __restrict__ Qjl,
                 const unsigned short* __restrict__ Kjl,
                 const unsigned short* __restrict__ Vc,
                 unsigned short* __restrict__ AO) {
  __shared__ __align__(16) unsigned short Kb[3][4096];   // [128 keys][32 kjl] x3 = 24 KB
  __shared__ __align__(16) unsigned short Vb[3][8192];   // [4][64 hd][32 s]  x3 = 48 KB
  __shared__ __align__(16) unsigned short Ps[4][4096];   // per-wave P strip [32][128] = 32 KB
  const int tid = threadIdx.x;
  const int lane = tid & 63, wv = tid >> 6;
  const int quad = lane >> 4, l15 = lane & 15;

  const int blk = blockIdx.x;            // 0..255
  const int bh = blk & 31;               // bh % 8 == xcd under round-robin: L2 locality
  const int u = blk >> 5;                // 0..7
  const int b = bh >> 4, h = bh & 15;

  const unsigned short* Kg = Kjl + (size_t)bh * S_ * KJL;        // [2048][32]
  const unsigned short* Vg = Vc + (size_t)bh * (64 * 64 * 32);   // [64][64][32]

  char* Pw = (char*)&Ps[wv][0];          // 8192 B wave-private strip
  const int pswz = l15 << 4;             // XOR swizzle bits 4-7 (involution)
  const floatx4 zz = {0.f, 0.f, 0.f, 0.f};

#define STAGE(bu, c) do {                                                   \
    const char* ks_ = (const char*)(Kg + (size_t)(c) * 4096);               \
    const char* vs_ = (const char*)(Vg + (size_t)(c) * 8192);               \
    char* kd_ = (char*)&Kb[bu][0];                                          \
    char* vd_ = (char*)&Vb[bu][0];                                          \
    async16(ks_ + tid * 16,         kd_ + tid * 16);                        \
    async16(ks_ + tid * 16 + 4096,  kd_ + tid * 16 + 4096);                 \
    async16(vs_ + tid * 16,         vd_ + tid * 16);                        \
    async16(vs_ + tid * 16 + 4096,  vd_ + tid * 16 + 4096);                 \
    async16(vs_ + tid * 16 + 8192,  vd_ + tid * 16 + 8192);                 \
    async16(vs_ + tid * 16 + 12288, vd_ + tid * 16 + 12288);                \
  } while (0)

  for (int ph = 0; ph < 2; ++ph) {
    const int g = ph ? (15 - u) : u;
    const int t = g * 4 + wv;            // this wave's q-tile: rows t*32..t*32+31
    const int nch = g + 1;
    const int lastc = g;

    bf16x8 aq[2];
    for (int qn = 0; qn < 2; ++qn)
      aq[qn] = *(const bf16x8*)&Qjl[(size_t)(bh * S_ + t * 32 + qn * 16 + l15) * KJL + quad * 8];

    floatx4 o[4][2] = {};
    floatx4 psum[2] = {};

    // prologue: stage chunks 0 (and 1), wait only for chunk 0
    STAGE(0, 0);
    if (nch > 1) {
      STAGE(1, 1);
      asm volatile("s_waitcnt vmcnt(6)" ::: "memory");
    } else {
      asm volatile("s_waitcnt vmcnt(0)" ::: "memory");
    }
    __builtin_amdgcn_s_barrier();

    for (int kt = 0; kt < nch; ++kt) {
      const int cur = kt % 3;
      if (kt + 2 < nch) STAGE((kt + 2) % 3, kt + 2);   // 2-deep prefetch

      const char* Kc = (const char*)&Kb[cur][0];
      const char* Vl = (const char*)&Vb[cur][0];

      // ---- QK^T ----
      bf16x8 ak[8];
      for (int sm = 0; sm < 8; ++sm)
        ak[sm] = *(const bf16x8*)(Kc + (sm * 16 + l15) * 64 + quad * 16);

      floatx4 sc[8][2];
      __builtin_amdgcn_s_setprio(1);
      for (int sm = 0; sm < 8; ++sm)
        for (int qn = 0; qn < 2; ++qn)
          sc[sm][qn] = __builtin_amdgcn_mfma_f32_16x16x32_bf16(ak[sm], aq[qn], zz, 0, 0, 0);
      __builtin_amdgcn_s_setprio(0);

      if (kt == lastc) {                 // causal mask within final chunk (r = t&3 = wv)
        for (int qn = 0; qn < 2; ++qn) {
          int qloc = wv * 32 + qn * 16 + l15;
          for (int sm = 0; sm < 8; ++sm)
            for (int i = 0; i < 4; ++i)
              if (sm * 16 + quad * 4 + i > qloc) sc[sm][qn][i] = -1e30f;
        }
      }

      // ---- softmax numerators -> P strip (swizzled) ----
      for (int qn = 0; qn < 2; ++qn) {
        for (int sm = 0; sm < 8; ++sm) {
          float p0 = __builtin_amdgcn_exp2f(sc[sm][qn][0]);
          float p1 = __builtin_amdgcn_exp2f(sc[sm][qn][1]);
          float p2 = __builtin_amdgcn_exp2f(sc[sm][qn][2]);
          float p3 = __builtin_amdgcn_exp2f(sc[sm][qn][3]);
          psum[qn][0] += p0; psum[qn][1] += p1;
          psum[qn][2] += p2; psum[qn][3] += p3;
          uint2v pk2 = {pkbf(p0, p1), pkbf(p2, p3)};
          *(uint2v*)(Pw + (qn * 16 + l15) * 256 + ((sm * 32 + quad * 8) ^ pswz)) = pk2;
        }
      }

      // ---- PV ----
      for (int ks = 0; ks < 4; ++ks) {
        bf16x8 bv[4];
        for (int md = 0; md < 4; ++md)
          bv[md] = *(const bf16x8*)(Vl + ks * 4096 + md * 1024 + l15 * 64 + quad * 16);
        bf16x8 bp[2];
        for (int qn = 0; qn < 2; ++qn)
          bp[qn] = *(const bf16x8*)(Pw + (qn * 16 + l15) * 256 + ((ks * 64 + quad * 16) ^ pswz));
        __builtin_amdgcn_s_setprio(1);
        for (int qn = 0; qn < 2; ++qn)
          for (int md = 0; md < 4; ++md)
            o[md][qn] = __builtin_amdgcn_mfma_f32_16x16x32_bf16(bv[md], bp[qn], o[md][qn], 0, 0, 0);
        __builtin_amdgcn_s_setprio(0);
      }

      // counted wait: require chunk kt+1 staged; allow chunk kt+2's 6 loads in flight
      if (kt + 2 < nch) {
        asm volatile("s_waitcnt vmcnt(6)" ::: "memory");
      } else {
        asm volatile("s_waitcnt vmcnt(0)" ::: "memory");
      }
      __builtin_amdgcn_s_barrier();
    }

    // ---- rowsums (full rows per wave; reduce across quads) ----
    float l0 = psum[0][0] + psum[0][1] + psum[0][2] + psum[0][3];
    float l1 = psum[1][0] + psum[1][1] + psum[1][2] + psum[1][3];
    l0 += __shfl_xor(l0, 16, 64); l0 += __shfl_xor(l0, 32, 64);
    l1 += __shfl_xor(l1, 16, 64); l1 += __shfl_xor(l1, 32, 64);

    // ---- normalize, transpose via own strip, write AO (every wave, own tile) ----
    {
      unsigned short* Pu = (unsigned short*)Pw;
      float inv0 = 1.f / l0;
      float inv1 = 1.f / l1;
      for (int qn = 0; qn < 2; ++qn) {
        float inv = qn ? inv1 : inv0;
        for (int md = 0; md < 4; ++md) {
          floatx4 s = o[md][qn];
          uint2v t4 = {pkbf(s[0] * inv, s[1] * inv),
                       pkbf(s[2] * inv, s[3] * inv)};
          *(uint2v*)&Pu[(qn * 16 + l15) * 72 + md * 16 + quad * 4] = t4;
        }
      }
      asm volatile("s_waitcnt lgkmcnt(0)" ::: "memory");
      int q = lane >> 1, hf = lane & 1;
      size_t gbase = ((size_t)(b * S_ + t * 32 + q)) * D_ + h * HD_ + hf * 32;
      for (int jj = 0; jj < 4; ++jj) {
        bf16x8 v = *(const bf16x8*)&Pu[q * 72 + hf * 32 + jj * 8];
        *(bf16x8*)&AO[gbase + jj * 8] = v;
      }
    }
  }
#undef STAGE
}

// ---------------- output projection: 64x128 tiles, BK=64 ----------------
__global__ __launch_bounds__(256, 2)
void proj_gemm_kernel(const unsigned short* __restrict__ A,
                      const unsigned short* __restrict__ Bt,
                      const float* __restrict__ bias,
                      float* __restrict__ out) {
  __shared__ __align__(16) unsigned short As[2][64 * 32];
  __shared__ __align__(16) unsigned short Bs[2][128 * 32];
  const int tid = threadIdx.x;
  const int lane = tid & 63, wv = tid >> 6;
  const int quad = lane >> 4, col = lane & 15;
  const int wm = wv >> 1, wn = wv & 1;
  const int m0 = blockIdx.y * 64, n0 = blockIdx.x * 128;

  floatx4 acc[2][4] = {};

  for (int kk = 0; kk < D_; kk += 64) {
    for (int it = 0; it < 2; ++it) {     // A: 64 rows x 64 k = 512 chunks
      int c = it * 256 + tid;
      int ks = c >> 8, row = (c >> 2) & 63, kc = c & 3;
      async16(A + (size_t)(m0 + row) * D_ + kk + ks * 32 + kc * 8,
              (unsigned short*)As + c * 8);
    }
    for (int it = 0; it < 4; ++it) {     // B: 128 rows x 64 k = 1024 chunks
      int c = it * 256 + tid;
      int ks = c >> 9, row = (c >> 2) & 127, kc = c & 3;
      async16(Bt + (size_t)(n0 + row) * D_ + kk + ks * 32 + kc * 8,
              (unsigned short*)Bs + c * 8);
    }
    asm volatile("s_waitcnt vmcnt(0)" ::: "memory");
    __syncthreads();
    for (int ks = 0; ks < 2; ++ks) {
      bf16x8 af[2], bfr[4];
      for (int mt = 0; mt < 2; ++mt)
        af[mt] = *(const bf16x8*)&As[ks][(wm * 32 + mt * 16 + col) * 32 + quad * 8];
      for (int nt = 0; nt < 4; ++nt)
        bfr[nt] = *(const bf16x8*)&Bs[ks][(wn * 64 + nt * 16 + col) * 32 + quad * 8];
      for (int mt = 0; mt < 2; ++mt)
        for (int nt = 0; nt < 4; ++nt)
          acc[mt][nt] = __builtin_amdgcn_mfma_f32_16x16x32_bf16(
              af[mt], bfr[nt], acc[mt][nt], 0, 0, 0);
    }
    __syncthreads();
  }

  for (int mt = 0; mt < 2; ++mt) {
    int gm0 = m0 + wm * 32 + mt * 16 + quad * 4;
    for (int nt = 0; nt < 4; ++nt) {
      int gn = n0 + wn * 64 + nt * 16 + col;
      float bs = bias[gn];
      for (int i = 0; i < 4; ++i)
        out[(size_t)(gm0 + i) * D_ + gn] = acc[mt][nt][i] + bs;
    }
  }
}

extern "C" void kernel_launch(void* const* d_in, const int* in_sizes, int n_in,
                              void* d_out, int out_size, void* d_ws, size_t ws_size,
                              hipStream_t stream) {
  (void)in_sizes; (void)n_in; (void)out_size; (void)ws_size;
  const float* hidden = (const float*)d_in[0];
  const float* W_attn = (const float*)d_in[1];
  const float* b_attn = (const float*)d_in[2];
  const float* S_proj = (const float*)d_in[3];
  const float* W_proj = (const float*)d_in[4];
  const float* b_proj = (const float*)d_in[5];
  float* out = (float*)d_out;

  char* ws = (char*)d_ws;
  unsigned short* hB    = (unsigned short*)(ws);                    //  8 MB
  unsigned short* Bt2   = (unsigned short*)(ws + (8u << 20));       //  4 MB
  unsigned short* WpT   = (unsigned short*)(ws + (12u << 20));      //  2 MB
  float*          bias2 = (float*)         (ws + (14u << 20));      //  4 KB
  unsigned short* Qjl   = (unsigned short*)(ws + (15u << 20));      //  4 MB
  unsigned short* Kjl   = (unsigned short*)(ws + (19u << 20));      //  4 MB
  unsigned short* Vc    = (unsigned short*)(ws + (23u << 20));      //  8 MB
  unsigned short* AO    = (unsigned short*)(ws + (31u << 20));      //  8 MB

  prep_kernel<<<2688, 256, 0, stream>>>(hidden, hB, W_attn, b_attn, S_proj,
                                        W_proj, Bt2, WpT, bias2);
  qkv2_gemm_kernel<<<dim3(N2 / 128, (B_ * S_) / 128), 256, 0, stream>>>(
      hB, Bt2, b_attn, bias2, Qjl, Kjl, Vc);
  attn_kernel<<<256, 256, 0, stream>>>(Qjl, Kjl, Vc, AO);
  proj_gemm_kernel<<<dim3(D_ / 128, (B_ * S_) / 64), 256, 0, stream>>>(
      AO, WpT, b_proj, out);
}

// Round 8
// 179.223 us; speedup vs baseline: 1.0190x; 1.0190x over previous
//
#include <hip/hip_runtime.h>
#include <hip/hip_bf16.h>
#include <stdint.h>

#define B_ 2
#define S_ 2048
#define D_ 1024
#define H_ 16
#define HD_ 64
#define KJL 32
#define N3 3072
#define N2 2048

typedef __attribute__((ext_vector_type(8))) __bf16 bf16x8;
typedef __attribute__((ext_vector_type(4))) float floatx4;
typedef __attribute__((ext_vector_type(4))) short short4v;
typedef __attribute__((ext_vector_type(2))) unsigned int uint2v;

__device__ __forceinline__ unsigned short f2b(float x) {
  union { float f; unsigned u; } v; v.f = x;
  unsigned r = v.u + 0x7fffu + ((v.u >> 16) & 1u);
  return (unsigned short)(r >> 16);
}

// pack two floats to packed bf16 (round via +0x8000): hi<<16 | lo
__device__ __forceinline__ unsigned int pkbf(float lo, float hi) {
  union { float f; unsigned u; } a, b;
  a.f = lo; b.f = hi;
  return __builtin_amdgcn_perm(b.u + 0x8000u, a.u + 0x8000u, 0x07060302u);
}

__device__ __forceinline__ void async16(const void* g, void* l) {
  __builtin_amdgcn_global_load_lds((__attribute__((address_space(1))) void*)(g),
                                   (__attribute__((address_space(3))) void*)(l),
                                   16, 0, 0);
}

// ---------------- fused prep: cvt4 | tcvt(V cols) | tcvt(W_proj) | wjl ----------------
__global__ __launch_bounds__(256)
void prep_kernel(const float* __restrict__ hidden, unsigned short* __restrict__ hB,
                 const float* __restrict__ W_attn, const float* __restrict__ b_attn,
                 const float* __restrict__ Sp, const float* __restrict__ W_proj,
                 unsigned short* __restrict__ Bt2, unsigned short* __restrict__ WpT,
                 float* __restrict__ bias2) {
  __shared__ float shmem[2048];
  const int bid = blockIdx.x;
  const int tid = threadIdx.x;

  if (bid < 512) {                      // ---- cvt4: hidden -> hB ----
    const int n4 = (B_ * S_ * D_) / 4;
    int i = bid * 256 + tid;
    for (; i < n4; i += 512 * 256) {
      float4 v = *(const float4*)(hidden + 4 * (size_t)i);
      short4v o = {(short)f2b(v.x), (short)f2b(v.y), (short)f2b(v.z), (short)f2b(v.w)};
      *(short4v*)(hB + 4 * (size_t)i) = o;
    }
  } else if (bid < 2560) {              // ---- tcvt: 32x32 transpose-convert tiles ----
    const float* in;
    unsigned short* out;
    int Cs, local;
    if (bid < 1536) { local = bid - 512;  in = W_attn + 2048; out = Bt2 + 1024 * 1024; Cs = N3; }
    else            { local = bid - 1536; in = W_proj;        out = WpT;               Cs = D_; }
    float (*t)[33] = (float(*)[33])shmem;
    int c0 = (local & 31) * 32, r0 = (local >> 5) * 32;
    int tx = tid & 31, ty = tid >> 5;
    for (int j = 0; j < 32; j += 8)
      t[ty + j][tx] = in[(size_t)(r0 + ty + j) * Cs + c0 + tx];
    __syncthreads();
    for (int j = 0; j < 32; j += 8)
      out[(size_t)(c0 + ty + j) * D_ + r0 + tx] = f2b(t[tx][ty + j]);
  } else {                              // ---- wjl: fused JL weights ----
    const int lb = bid - 2560;          // 0..127
    const int part = lb >> 6;           // 0 = Q, 1 = K
    const int h = (lb >> 2) & 15;
    const int dc = lb & 3;
    for (int i = tid; i < 32 * 64; i += 256) shmem[i] = Sp[i];
    __syncthreads();
    const float scale = part ? 1.0f : 0.125f * 1.44269504f;
    const int d = dc * 256 + tid;
    float w[64];
    const float* src = W_attn + (size_t)d * N3 + part * D_ + h * 64;
    for (int j = 0; j < 16; ++j) {
      float4 v = *(const float4*)&src[j * 4];
      w[j * 4 + 0] = v.x; w[j * 4 + 1] = v.y; w[j * 4 + 2] = v.z; w[j * 4 + 3] = v.w;
    }
    const int nbase = part * 512 + h * 32;
    for (int kjl = 0; kjl < 32; ++kjl) {
      float acc = 0.f;
      for (int hd = 0; hd < 64; ++hd) acc += w[hd] * shmem[kjl * 64 + hd];
      Bt2[(size_t)(nbase + kjl) * D_ + d] = f2b(acc * scale);
    }
    if (dc == 0 && tid < 32) {
      float acc = 0.f;
      for (int hd = 0; hd < 64; ++hd) acc += b_attn[part * D_ + h * 64 + hd] * shmem[tid * 64 + hd];
      bias2[nbase + tid] = acc * scale;
    }
  }
}

// ---------------- fused qkv+JL GEMM: 128x128 tiles, BK=64 ----------------
__global__ __launch_bounds__(256, 2)
void qkv2_gemm_kernel(const unsigned short* __restrict__ A,
                      const unsigned short* __restrict__ Bt,
                      const float* __restrict__ b_attn,
                      const float* __restrict__ bias2,
                      unsigned short* __restrict__ Qjl,
                      unsigned short* __restrict__ Kjl,
                      unsigned short* __restrict__ Vc) {
  __shared__ __align__(16) unsigned short As[2][128 * 32];
  __shared__ __align__(16) unsigned short Bs[2][128 * 32];
  const int tid = threadIdx.x;
  const int lane = tid & 63, wv = tid >> 6;
  const int quad = lane >> 4, col = lane & 15;
  const int wm = wv >> 1, wn = wv & 1;
  const int m0 = blockIdx.y * 128, n0 = blockIdx.x * 128;

  floatx4 acc[4][4] = {};

  for (int kk = 0; kk < D_; kk += 64) {
    for (int it = 0; it < 4; ++it) {
      int c = it * 256 + tid;            // 0..1023
      int ks = c >> 9, row = (c >> 2) & 127, kc = c & 3;
      async16(A + (size_t)(m0 + row) * D_ + kk + ks * 32 + kc * 8,
              (unsigned short*)As + c * 8);
    }
    for (int it = 0; it < 4; ++it) {
      int c = it * 256 + tid;
      int ks = c >> 9, row = (c >> 2) & 127, kc = c & 3;
      async16(Bt + (size_t)(n0 + row) * D_ + kk + ks * 32 + kc * 8,
              (unsigned short*)Bs + c * 8);
    }
    asm volatile("s_waitcnt vmcnt(0)" ::: "memory");
    __syncthreads();
    for (int ks = 0; ks < 2; ++ks) {
      bf16x8 af[4], bfr[4];
      for (int mt = 0; mt < 4; ++mt)
        af[mt] = *(const bf16x8*)&As[ks][(wm * 64 + mt * 16 + col) * 32 + quad * 8];
      for (int nt = 0; nt < 4; ++nt)
        bfr[nt] = *(const bf16x8*)&Bs[ks][(wn * 64 + nt * 16 + col) * 32 + quad * 8];
      for (int mt = 0; mt < 4; ++mt)
        for (int nt = 0; nt < 4; ++nt)
          acc[mt][nt] = __builtin_amdgcn_mfma_f32_16x16x32_bf16(
              af[mt], bfr[nt], acc[mt][nt], 0, 0, 0);
    }
    __syncthreads();
  }

  const int pq = n0 >> 9;  // 0=Q, 1=K, >=2 -> V
  for (int mt = 0; mt < 4; ++mt) {
    int gm0 = m0 + wm * 64 + mt * 16 + quad * 4;
    int b = gm0 >> 11, s = gm0 & (S_ - 1);
    for (int nt = 0; nt < 4; ++nt) {
      int gn = n0 + wn * 64 + nt * 16 + col;
      if (pq >= 2) {
        int vcol = gn - 1024;
        float bs = b_attn[2048 + vcol];
        int h = vcol >> 6, hd = vcol & 63;
        short4v vv;
        for (int i = 0; i < 4; ++i)
          vv[i] = (short)f2b(acc[mt][nt][i] + bs);
        size_t idx = ((((size_t)(b * H_ + h) * 64 + (s >> 5)) * 64 + hd) * 32 + (s & 31));
        *(short4v*)&Vc[idx] = vv;
      } else {
        float bs = bias2[gn];
        int gl = gn & 511;
        int h = gl >> 5, kjl = gl & 31;
        unsigned short* dst = pq ? Kjl : Qjl;
        size_t base = ((size_t)(b * H_ + h) * S_ + s) * KJL + kjl;
        for (int i = 0; i < 4; ++i)
          dst[base + (size_t)i * KJL] = f2b(acc[mt][nt][i] + bs);
      }
    }
  }
}

// ---------------- 8-wave two-phase flash attention: 2 waves/SIMD, 16-row tiles ----------------
// ROUND 18 DIAGNOSIS: round 17's deterministic 17-chunk schedule + counted vmcnt was
// structurally perfect (no spill, uniform work) and DID NOT MOVE (43.8us): with 104KB
// LDS -> 1 block/CU -> 4 waves = exactly 1 WAVE PER SIMD. Zero TLP: the per-chunk
// serial chain (ds_read lat 120cy + 8..16 MFMA + 64 exp2 + P round-trip + PV) is
// fully exposed, ~6K cyc/chunk. ALL prior variants averaged ~1 wave/SIMD -- which is
// why three different structures converged to ~43us.
// FIX: 8 waves/block (512 thr), tiles shrink to 16 q-rows (t = g*8+wv). Same uniform
// two-phase frame (g=u then 15-u, 17 chunks), same triple-buffered K/V + counted
// vmcnt(3) + raw s_barrier. LDS unchanged 104KB -> 1 block/CU -> 2 waves/SIMD, and
// per-wave chunk work halves. Expect ~2-3x on the latency-bound chain.
// LESSONS ENCODED: r13 register prefetch spills; r16 don't add lgkm round-trips;
// r11 no global merge in-kernel; r8 no min-waves cap; r5 no runtime-indexed arrays.
__global__ __launch_bounds__(512, 1)
void attn_kernel(const unsigned short* __restrict__ Qjl,
                 const unsigned short* __restrict__ Kjl,
                 const unsigned short* __restrict__ Vc,
                 unsigned short* __restrict__ AO) {
  __shared__ __align__(16) unsigned short Kb[3][4096];   // [128 keys][32 kjl] x3 = 24 KB
  __shared__ __align__(16) unsigned short Vb[3][8192];   // [4][64 hd][32 s]  x3 = 48 KB
  __shared__ __align__(16) unsigned short Ps[8][2048];   // per-wave strip [16 q][128 k] = 32 KB
  const int tid = threadIdx.x;
  const int lane = tid & 63, wv = tid >> 6;              // wv 0..7
  const int quad = lane >> 4, l15 = lane & 15;

  const int blk = blockIdx.x;            // 0..255
  const int bh = blk & 31;               // bh % 8 == xcd under round-robin: L2 locality
  const int u = blk >> 5;                // 0..7
  const int b = bh >> 4, h = bh & 15;

  const unsigned short* Kg = Kjl + (size_t)bh * S_ * KJL;        // [2048][32]
  const unsigned short* Vg = Vc + (size_t)bh * (64 * 64 * 32);   // [64][64][32]

  char* Pw = (char*)&Ps[wv][0];          // 4096 B wave-private strip
  const int pswz = l15 << 4;             // XOR swizzle bits 4-7 (involution)
  const floatx4 zz = {0.f, 0.f, 0.f, 0.f};

#define STAGE(bu, c) do {                                                   \
    const char* ks_ = (const char*)(Kg + (size_t)(c) * 4096);               \
    const char* vs_ = (const char*)(Vg + (size_t)(c) * 8192);               \
    char* kd_ = (char*)&Kb[bu][0];                                          \
    char* vd_ = (char*)&Vb[bu][0];                                          \
    async16(ks_ + tid * 16,        kd_ + tid * 16);                         \
    async16(vs_ + tid * 16,        vd_ + tid * 16);                         \
    async16(vs_ + tid * 16 + 8192, vd_ + tid * 16 + 8192);                  \
  } while (0)

  for (int ph = 0; ph < 2; ++ph) {
    const int g = ph ? (15 - u) : u;
    const int t = g * 8 + wv;            // 16-row tile: rows t*16..t*16+15
    const int nch = g + 1;
    const int lastc = g;

    bf16x8 aq = *(const bf16x8*)&Qjl[(size_t)(bh * S_ + t * 16 + l15) * KJL + quad * 8];

    floatx4 o[4] = {};
    floatx4 psum = {};

    // prologue: stage chunks 0 (and 1), wait only for chunk 0
    STAGE(0, 0);
    if (nch > 1) {
      STAGE(1, 1);
      asm volatile("s_waitcnt vmcnt(3)" ::: "memory");
    } else {
      asm volatile("s_waitcnt vmcnt(0)" ::: "memory");
    }
    __builtin_amdgcn_s_barrier();

    for (int kt = 0; kt < nch; ++kt) {
      const int cur = kt % 3;
      if (kt + 2 < nch) STAGE((kt + 2) % 3, kt + 2);   // 2-deep prefetch

      const char* Kc = (const char*)&Kb[cur][0];
      const char* Vl = (const char*)&Vb[cur][0];

      // ---- QK^T: sc[sm][i] = S[key = sm*16+quad*4+i][q = l15] ----
      bf16x8 ak[8];
      for (int sm = 0; sm < 8; ++sm)
        ak[sm] = *(const bf16x8*)(Kc + (sm * 16 + l15) * 64 + quad * 16);

      floatx4 sc[8];
      __builtin_amdgcn_s_setprio(1);
      for (int sm = 0; sm < 8; ++sm)
        sc[sm] = __builtin_amdgcn_mfma_f32_16x16x32_bf16(ak[sm], aq, zz, 0, 0, 0);
      __builtin_amdgcn_s_setprio(0);

      if (kt == lastc) {                 // causal mask within final chunk
        int qloc = wv * 16 + l15;        // q-row within the group's 128 rows
        for (int sm = 0; sm < 8; ++sm)
          for (int i = 0; i < 4; ++i)
            if (sm * 16 + quad * 4 + i > qloc) sc[sm][i] = -1e30f;
      }

      // ---- softmax numerators -> P strip (swizzled) ----
      for (int sm = 0; sm < 8; ++sm) {
        float p0 = __builtin_amdgcn_exp2f(sc[sm][0]);
        float p1 = __builtin_amdgcn_exp2f(sc[sm][1]);
        float p2 = __builtin_amdgcn_exp2f(sc[sm][2]);
        float p3 = __builtin_amdgcn_exp2f(sc[sm][3]);
        psum[0] += p0; psum[1] += p1; psum[2] += p2; psum[3] += p3;
        uint2v pk2 = {pkbf(p0, p1), pkbf(p2, p3)};
        *(uint2v*)(Pw + l15 * 256 + ((sm * 32 + quad * 8) ^ pswz)) = pk2;
      }

      // ---- PV: o[md][i] = O[hd = md*16+quad*4+i][q = l15] ----
      for (int ks = 0; ks < 4; ++ks) {
        bf16x8 bv[4];
        for (int md = 0; md < 4; ++md)
          bv[md] = *(const bf16x8*)(Vl + ks * 4096 + md * 1024 + l15 * 64 + quad * 16);
        bf16x8 bp = *(const bf16x8*)(Pw + l15 * 256 + ((ks * 64 + quad * 16) ^ pswz));
        __builtin_amdgcn_s_setprio(1);
        for (int md = 0; md < 4; ++md)
          o[md] = __builtin_amdgcn_mfma_f32_16x16x32_bf16(bv[md], bp, o[md], 0, 0, 0);
        __builtin_amdgcn_s_setprio(0);
      }

      // counted wait: require chunk kt+1 staged; allow chunk kt+2's 3 loads in flight
      if (kt + 2 < nch) {
        asm volatile("s_waitcnt vmcnt(3)" ::: "memory");
      } else {
        asm volatile("s_waitcnt vmcnt(0)" ::: "memory");
      }
      __builtin_amdgcn_s_barrier();
    }

    // ---- rowsum: reduce across quads (rows are l15-resident) ----
    float l0 = psum[0] + psum[1] + psum[2] + psum[3];
    l0 += __shfl_xor(l0, 16, 64);
    l0 += __shfl_xor(l0, 32, 64);
    float inv = 1.f / l0;

    // ---- normalize, transpose via own strip [16 q][64 hd], write AO ----
    {
      const int eswz = (l15 & 7) << 4;   // bank swizzle for 128B-stride rows
      for (int md = 0; md < 4; ++md) {
        uint2v t4 = {pkbf(o[md][0] * inv, o[md][1] * inv),
                     pkbf(o[md][2] * inv, o[md][3] * inv)};
        *(uint2v*)(Pw + l15 * 128 + ((md * 32 + quad * 8) ^ eswz)) = t4;
      }
      asm volatile("s_waitcnt lgkmcnt(0)" ::: "memory");
      int q = lane >> 2, j = lane & 3;
      size_t gbase = ((size_t)(b * S_ + t * 16 + q)) * D_ + h * HD_;
      for (int half = 0; half < 2; ++half) {
        bf16x8 v = *(const bf16x8*)(Pw + q * 128 + ((half * 64 + j * 16) ^ ((q & 7) << 4)));
        *(bf16x8*)&AO[gbase + half * 32 + j * 8] = v;
      }
    }
  }
#undef STAGE
}

// ---------------- output projection: 64x128 tiles, BK=64 ----------------
__global__ __launch_bounds__(256, 2)
void proj_gemm_kernel(const unsigned short* __restrict__ A,
                      const unsigned short* __restrict__ Bt,
                      const float* __restrict__ bias,
                      float* __restrict__ out) {
  __shared__ __align__(16) unsigned short As[2][64 * 32];
  __shared__ __align__(16) unsigned short Bs[2][128 * 32];
  const int tid = threadIdx.x;
  const int lane = tid & 63, wv = tid >> 6;
  const int quad = lane >> 4, col = lane & 15;
  const int wm = wv >> 1, wn = wv & 1;
  const int m0 = blockIdx.y * 64, n0 = blockIdx.x * 128;

  floatx4 acc[2][4] = {};

  for (int kk = 0; kk < D_; kk += 64) {
    for (int it = 0; it < 2; ++it) {     // A: 64 rows x 64 k = 512 chunks
      int c = it * 256 + tid;
      int ks = c >> 8, row = (c >> 2) & 63, kc = c & 3;
      async16(A + (size_t)(m0 + row) * D_ + kk + ks * 32 + kc * 8,
              (unsigned short*)As + c * 8);
    }
    for (int it = 0; it < 4; ++it) {     // B: 128 rows x 64 k = 1024 chunks
      int c = it * 256 + tid;
      int ks = c >> 9, row = (c >> 2) & 127, kc = c & 3;
      async16(Bt + (size_t)(n0 + row) * D_ + kk + ks * 32 + kc * 8,
              (unsigned short*)Bs + c * 8);
    }
    asm volatile("s_waitcnt vmcnt(0)" ::: "memory");
    __syncthreads();
    for (int ks = 0; ks < 2; ++ks) {
      bf16x8 af[2], bfr[4];
      for (int mt = 0; mt < 2; ++mt)
        af[mt] = *(const bf16x8*)&As[ks][(wm * 32 + mt * 16 + col) * 32 + quad * 8];
      for (int nt = 0; nt < 4; ++nt)
        bfr[nt] = *(const bf16x8*)&Bs[ks][(wn * 64 + nt * 16 + col) * 32 + quad * 8];
      for (int mt = 0; mt < 2; ++mt)
        for (int nt = 0; nt < 4; ++nt)
          acc[mt][nt] = __builtin_amdgcn_mfma_f32_16x16x32_bf16(
              af[mt], bfr[nt], acc[mt][nt], 0, 0, 0);
    }
    __syncthreads();
  }

  for (int mt = 0; mt < 2; ++mt) {
    int gm0 = m0 + wm * 32 + mt * 16 + quad * 4;
    for (int nt = 0; nt < 4; ++nt) {
      int gn = n0 + wn * 64 + nt * 16 + col;
      float bs = bias[gn];
      for (int i = 0; i < 4; ++i)
        out[(size_t)(gm0 + i) * D_ + gn] = acc[mt][nt][i] + bs;
    }
  }
}

extern "C" void kernel_launch(void* const* d_in, const int* in_sizes, int n_in,
                              void* d_out, int out_size, void* d_ws, size_t ws_size,
                              hipStream_t stream) {
  (void)in_sizes; (void)n_in; (void)out_size; (void)ws_size;
  const float* hidden = (const float*)d_in[0];
  const float* W_attn = (const float*)d_in[1];
  const float* b_attn = (const float*)d_in[2];
  const float* S_proj = (const float*)d_in[3];
  const float* W_proj = (const float*)d_in[4];
  const float* b_proj = (const float*)d_in[5];
  float* out = (float*)d_out;

  char* ws = (char*)d_ws;
  unsigned short* hB    = (unsigned short*)(ws);                    //  8 MB
  unsigned short* Bt2   = (unsigned short*)(ws + (8u << 20));       //  4 MB
  unsigned short* WpT   = (unsigned short*)(ws + (12u << 20));      //  2 MB
  float*          bias2 = (float*)         (ws + (14u << 20));      //  4 KB
  unsigned short* Qjl   = (unsigned short*)(ws + (15u << 20));      //  4 MB
  unsigned short* Kjl   = (unsigned short*)(ws + (19u << 20));      //  4 MB
  unsigned short* Vc    = (unsigned short*)(ws + (23u << 20));      //  8 MB
  unsigned short* AO    = (unsigned short*)(ws + (31u << 20));      //  8 MB

  prep_kernel<<<2688, 256, 0, stream>>>(hidden, hB, W_attn, b_attn, S_proj,
                                        W_proj, Bt2, WpT, bias2);
  qkv2_gemm_kernel<<<dim3(N2 / 128, (B_ * S_) / 128), 256, 0, stream>>>(
      hB, Bt2, b_attn, bias2, Qjl, Kjl, Vc);
  attn_kernel<<<256, 512, 0, stream>>>(Qjl, Kjl, Vc, AO);
  proj_gemm_kernel<<<dim3(D_ / 128, (B_ * S_) / 64), 256, 0, stream>>>(
      AO, WpT, b_proj, out);
}

// Round 9
// 177.886 us; speedup vs baseline: 1.0266x; 1.0075x over previous
//
#include <hip/hip_runtime.h>
#include <hip/hip_bf16.h>
#include <stdint.h>

#define B_ 2
#define S_ 2048
#define D_ 1024
#define H_ 16
#define HD_ 64
#define KJL 32
#define N3 3072
#define N2 2048

typedef __attribute__((ext_vector_type(8))) __bf16 bf16x8;
typedef __attribute__((ext_vector_type(4))) float floatx4;
typedef __attribute__((ext_vector_type(4))) short short4v;
typedef __attribute__((ext_vector_type(2))) unsigned int uint2v;

__device__ __forceinline__ unsigned short f2b(float x) {
  union { float f; unsigned u; } v; v.f = x;
  unsigned r = v.u + 0x7fffu + ((v.u >> 16) & 1u);
  return (unsigned short)(r >> 16);
}

// pack two floats to packed bf16 (round via +0x8000): hi<<16 | lo
__device__ __forceinline__ unsigned int pkbf(float lo, float hi) {
  union { float f; unsigned u; } a, b;
  a.f = lo; b.f = hi;
  return __builtin_amdgcn_perm(b.u + 0x8000u, a.u + 0x8000u, 0x07060302u);
}

__device__ __forceinline__ void async16(const void* g, void* l) {
  __builtin_amdgcn_global_load_lds((__attribute__((address_space(1))) void*)(g),
                                   (__attribute__((address_space(3))) void*)(l),
                                   16, 0, 0);
}

// ---------------- fused prep: cvt4 | tcvt(V cols) | tcvt(W_proj) | wjl ----------------
__global__ __launch_bounds__(256)
void prep_kernel(const float* __restrict__ hidden, unsigned short* __restrict__ hB,
                 const float* __restrict__ W_attn, const float* __restrict__ b_attn,
                 const float* __restrict__ Sp, const float* __restrict__ W_proj,
                 unsigned short* __restrict__ Bt2, unsigned short* __restrict__ WpT,
                 float* __restrict__ bias2) {
  __shared__ float shmem[2048];
  const int bid = blockIdx.x;
  const int tid = threadIdx.x;

  if (bid < 512) {                      // ---- cvt4: hidden -> hB ----
    const int n4 = (B_ * S_ * D_) / 4;
    int i = bid * 256 + tid;
    for (; i < n4; i += 512 * 256) {
      float4 v = *(const float4*)(hidden + 4 * (size_t)i);
      short4v o = {(short)f2b(v.x), (short)f2b(v.y), (short)f2b(v.z), (short)f2b(v.w)};
      *(short4v*)(hB + 4 * (size_t)i) = o;
    }
  } else if (bid < 2560) {              // ---- tcvt: 32x32 transpose-convert tiles ----
    const float* in;
    unsigned short* out;
    int Cs, local;
    if (bid < 1536) { local = bid - 512;  in = W_attn + 2048; out = Bt2 + 1024 * 1024; Cs = N3; }
    else            { local = bid - 1536; in = W_proj;        out = WpT;               Cs = D_; }
    float (*t)[33] = (float(*)[33])shmem;
    int c0 = (local & 31) * 32, r0 = (local >> 5) * 32;
    int tx = tid & 31, ty = tid >> 5;
    for (int j = 0; j < 32; j += 8)
      t[ty + j][tx] = in[(size_t)(r0 + ty + j) * Cs + c0 + tx];
    __syncthreads();
    for (int j = 0; j < 32; j += 8)
      out[(size_t)(c0 + ty + j) * D_ + r0 + tx] = f2b(t[tx][ty + j]);
  } else {                              // ---- wjl: fused JL weights ----
    const int lb = bid - 2560;          // 0..127
    const int part = lb >> 6;           // 0 = Q, 1 = K
    const int h = (lb >> 2) & 15;
    const int dc = lb & 3;
    for (int i = tid; i < 32 * 64; i += 256) shmem[i] = Sp[i];
    __syncthreads();
    const float scale = part ? 1.0f : 0.125f * 1.44269504f;
    const int d = dc * 256 + tid;
    float w[64];
    const float* src = W_attn + (size_t)d * N3 + part * D_ + h * 64;
    for (int j = 0; j < 16; ++j) {
      float4 v = *(const float4*)&src[j * 4];
      w[j * 4 + 0] = v.x; w[j * 4 + 1] = v.y; w[j * 4 + 2] = v.z; w[j * 4 + 3] = v.w;
    }
    const int nbase = part * 512 + h * 32;
    for (int kjl = 0; kjl < 32; ++kjl) {
      float acc = 0.f;
      for (int hd = 0; hd < 64; ++hd) acc += w[hd] * shmem[kjl * 64 + hd];
      Bt2[(size_t)(nbase + kjl) * D_ + d] = f2b(acc * scale);
    }
    if (dc == 0 && tid < 32) {
      float acc = 0.f;
      for (int hd = 0; hd < 64; ++hd) acc += b_attn[part * D_ + h * 64 + hd] * shmem[tid * 64 + hd];
      bias2[nbase + tid] = acc * scale;
    }
  }
}

// ---------------- fused qkv+JL GEMM: 128x128 tiles, BK=64 ----------------
__global__ __launch_bounds__(256, 2)
void qkv2_gemm_kernel(const unsigned short* __restrict__ A,
                      const unsigned short* __restrict__ Bt,
                      const float* __restrict__ b_attn,
                      const float* __restrict__ bias2,
                      unsigned short* __restrict__ Qjl,
                      unsigned short* __restrict__ Kjl,
                      unsigned short* __restrict__ Vc) {
  __shared__ __align__(16) unsigned short As[2][128 * 32];
  __shared__ __align__(16) unsigned short Bs[2][128 * 32];
  const int tid = threadIdx.x;
  const int lane = tid & 63, wv = tid >> 6;
  const int quad = lane >> 4, col = lane & 15;
  const int wm = wv >> 1, wn = wv & 1;
  const int m0 = blockIdx.y * 128, n0 = blockIdx.x * 128;

  floatx4 acc[4][4] = {};

  for (int kk = 0; kk < D_; kk += 64) {
    for (int it = 0; it < 4; ++it) {
      int c = it * 256 + tid;            // 0..1023
      int ks = c >> 9, row = (c >> 2) & 127, kc = c & 3;
      async16(A + (size_t)(m0 + row) * D_ + kk + ks * 32 + kc * 8,
              (unsigned short*)As + c * 8);
    }
    for (int it = 0; it < 4; ++it) {
      int c = it * 256 + tid;
      int ks = c >> 9, row = (c >> 2) & 127, kc = c & 3;
      async16(Bt + (size_t)(n0 + row) * D_ + kk + ks * 32 + kc * 8,
              (unsigned short*)Bs + c * 8);
    }
    asm volatile("s_waitcnt vmcnt(0)" ::: "memory");
    __syncthreads();
    for (int ks = 0; ks < 2; ++ks) {
      bf16x8 af[4], bfr[4];
      for (int mt = 0; mt < 4; ++mt)
        af[mt] = *(const bf16x8*)&As[ks][(wm * 64 + mt * 16 + col) * 32 + quad * 8];
      for (int nt = 0; nt < 4; ++nt)
        bfr[nt] = *(const bf16x8*)&Bs[ks][(wn * 64 + nt * 16 + col) * 32 + quad * 8];
      for (int mt = 0; mt < 4; ++mt)
        for (int nt = 0; nt < 4; ++nt)
          acc[mt][nt] = __builtin_amdgcn_mfma_f32_16x16x32_bf16(
              af[mt], bfr[nt], acc[mt][nt], 0, 0, 0);
    }
    __syncthreads();
  }

  const int pq = n0 >> 9;  // 0=Q, 1=K, >=2 -> V
  for (int mt = 0; mt < 4; ++mt) {
    int gm0 = m0 + wm * 64 + mt * 16 + quad * 4;
    int b = gm0 >> 11, s = gm0 & (S_ - 1);
    for (int nt = 0; nt < 4; ++nt) {
      int gn = n0 + wn * 64 + nt * 16 + col;
      if (pq >= 2) {
        int vcol = gn - 1024;
        float bs = b_attn[2048 + vcol];
        int h = vcol >> 6, hd = vcol & 63;
        short4v vv;
        for (int i = 0; i < 4; ++i)
          vv[i] = (short)f2b(acc[mt][nt][i] + bs);
        size_t idx = ((((size_t)(b * H_ + h) * 64 + (s >> 5)) * 64 + hd) * 32 + (s & 31));
        *(short4v*)&Vc[idx] = vv;
      } else {
        float bs = bias2[gn];
        int gl = gn & 511;
        int h = gl >> 5, kjl = gl & 31;
        unsigned short* dst = pq ? Kjl : Qjl;
        size_t base = ((size_t)(b * H_ + h) * S_ + s) * KJL + kjl;
        for (int i = 0; i < 4; ++i)
          dst[base + (size_t)i * KJL] = f2b(acc[mt][nt][i] + bs);
      }
    }
  }
}

// ---------------- 2-blocks/CU flash attention: 4 waves, 64 rows/block, decoupled barriers ----------------
// ROUND 19 DIAGNOSIS: r18 (8 waves = 2/SIMD) was time-IDENTICAL to r17 (1/SIMD): 43.5us.
// Per-CU pipe sum (VALU 24K + MFMA 11K + LDS ~39K + conflicts 18K ~= 92K of 104K cyc)
// shows the pipes run back-to-back SERIALLY under ONE barrier domain: every wave
// stalls at the same per-chunk drain; nothing fills the gaps.
// FIX: split into two INDEPENDENT 4-wave blocks per CU. Grid 512 = 32 bh x 16 v;
// block v owns 64 q-rows (4 waves x 16-row tiles), runs phase v then 31-v =>
// nch(v)+nch(31-v) = (v/2+1)+((31-v)/2+1) = 17 chunks EVERY block, by construction
// (no co-residency assumption). LDS = K dbuf 16K + V dbuf 32K + P 4x4K = 64KB ->
// capacity guarantees 2 blocks/CU; their barriers/vmcnt are DECOUPLED, so block A's
// stage-drain overlaps block B's compute. Simple dbuf schedule (STAGE(next) ->
// compute -> vmcnt(0) -> s_barrier): the drain is hidden by the sibling block.
// LESSONS ENCODED: r13 register prefetch spills; r16 keep full-chunk P strips;
// r11 no global merge in-kernel; r8 no min-waves cap; r5 no runtime-indexed arrays.
__global__ __launch_bounds__(256, 2)
void attn_kernel(const unsigned short* __restrict__ Qjl,
                 const unsigned short* __restrict__ Kjl,
                 const unsigned short* __restrict__ Vc,
                 unsigned short* __restrict__ AO) {
  __shared__ __align__(16) unsigned short Kb[2][4096];   // [128 keys][32 kjl] x2 = 16 KB
  __shared__ __align__(16) unsigned short Vb[2][8192];   // [4][64 hd][32 s]  x2 = 32 KB
  __shared__ __align__(16) unsigned short Ps[4][2048];   // per-wave strip [16 q][128 k] = 16 KB
  const int tid = threadIdx.x;
  const int lane = tid & 63, wv = tid >> 6;              // wv 0..3
  const int quad = lane >> 4, l15 = lane & 15;

  const int blk = blockIdx.x;            // 0..511
  const int bh = blk & 31;               // bh % 8 == xcd under round-robin: L2 locality
  const int v = blk >> 5;                // 0..15
  const int b = bh >> 4, h = bh & 15;

  const unsigned short* Kg = Kjl + (size_t)bh * S_ * KJL;        // [2048][32]
  const unsigned short* Vg = Vc + (size_t)bh * (64 * 64 * 32);   // [64][64][32]

  char* Pw = (char*)&Ps[wv][0];          // 4096 B wave-private strip
  const int pswz = l15 << 4;             // XOR swizzle bits 4-7 (involution; rows 256B)
  const floatx4 zz = {0.f, 0.f, 0.f, 0.f};

#define STAGE(bu, c) do {                                                   \
    const char* ks_ = (const char*)(Kg + (size_t)(c) * 4096);               \
    const char* vs_ = (const char*)(Vg + (size_t)(c) * 8192);               \
    char* kd_ = (char*)&Kb[bu][0];                                          \
    char* vd_ = (char*)&Vb[bu][0];                                          \
    async16(ks_ + tid * 16,         kd_ + tid * 16);                        \
    async16(ks_ + tid * 16 + 4096,  kd_ + tid * 16 + 4096);                 \
    async16(vs_ + tid * 16,         vd_ + tid * 16);                        \
    async16(vs_ + tid * 16 + 4096,  vd_ + tid * 16 + 4096);                 \
    async16(vs_ + tid * 16 + 8192,  vd_ + tid * 16 + 8192);                 \
    async16(vs_ + tid * 16 + 12288, vd_ + tid * 16 + 12288);                \
  } while (0)

  for (int ph = 0; ph < 2; ++ph) {
    const int gv = ph ? (31 - v) : v;    // 64-row group 0..31
    const int t16 = gv * 4 + wv;         // 16-row tile: rows t16*16..t16*16+15
    const int nch = (gv >> 1) + 1;       // chunks of 128 keys (identical for all 4 waves)
    const int lastc = nch - 1;
    const int qbase = (gv & 1) * 64 + wv * 16;  // row offset within last chunk's keys

    bf16x8 aq = *(const bf16x8*)&Qjl[(size_t)(bh * S_ + t16 * 16 + l15) * KJL + quad * 8];

    floatx4 o[4] = {};
    floatx4 psum = {};

    // prologue: stage chunk 0
    STAGE(0, 0);
    asm volatile("s_waitcnt vmcnt(0)" ::: "memory");
    __builtin_amdgcn_s_barrier();

    int cur = 0;
    for (int kt = 0; kt < nch; ++kt) {
      if (kt + 1 < nch) STAGE(cur ^ 1, kt + 1);   // prefetch overlaps compute

      const char* Kc = (const char*)&Kb[cur][0];
      const char* Vl = (const char*)&Vb[cur][0];

      // ---- QK^T: sc[sm][i] = S[key = sm*16+quad*4+i][q = l15] ----
      bf16x8 ak[8];
      for (int sm = 0; sm < 8; ++sm)
        ak[sm] = *(const bf16x8*)(Kc + (sm * 16 + l15) * 64 + quad * 16);

      floatx4 sc[8];
      __builtin_amdgcn_s_setprio(1);
      for (int sm = 0; sm < 8; ++sm)
        sc[sm] = __builtin_amdgcn_mfma_f32_16x16x32_bf16(ak[sm], aq, zz, 0, 0, 0);
      __builtin_amdgcn_s_setprio(0);

      if (kt == lastc) {                 // causal mask within final chunk
        int qloc = qbase + l15;
        for (int sm = 0; sm < 8; ++sm)
          for (int i = 0; i < 4; ++i)
            if (sm * 16 + quad * 4 + i > qloc) sc[sm][i] = -1e30f;
      }

      // ---- softmax numerators -> P strip (swizzled) ----
      for (int sm = 0; sm < 8; ++sm) {
        float p0 = __builtin_amdgcn_exp2f(sc[sm][0]);
        float p1 = __builtin_amdgcn_exp2f(sc[sm][1]);
        float p2 = __builtin_amdgcn_exp2f(sc[sm][2]);
        float p3 = __builtin_amdgcn_exp2f(sc[sm][3]);
        psum[0] += p0; psum[1] += p1; psum[2] += p2; psum[3] += p3;
        uint2v pk2 = {pkbf(p0, p1), pkbf(p2, p3)};
        *(uint2v*)(Pw + l15 * 256 + ((sm * 32 + quad * 8) ^ pswz)) = pk2;
      }

      // ---- PV: o[md][i] = O[hd = md*16+quad*4+i][q = l15] ----
      for (int ks = 0; ks < 4; ++ks) {
        bf16x8 bv[4];
        for (int md = 0; md < 4; ++md)
          bv[md] = *(const bf16x8*)(Vl + ks * 4096 + md * 1024 + l15 * 64 + quad * 16);
        bf16x8 bp = *(const bf16x8*)(Pw + l15 * 256 + ((ks * 64 + quad * 16) ^ pswz));
        __builtin_amdgcn_s_setprio(1);
        for (int md = 0; md < 4; ++md)
          o[md] = __builtin_amdgcn_mfma_f32_16x16x32_bf16(bv[md], bp, o[md], 0, 0, 0);
        __builtin_amdgcn_s_setprio(0);
      }

      asm volatile("s_waitcnt vmcnt(0)" ::: "memory");
      __builtin_amdgcn_s_barrier();
      cur ^= 1;
    }

    // ---- rowsum: reduce across quads (rows are l15-resident) ----
    float l0 = psum[0] + psum[1] + psum[2] + psum[3];
    l0 += __shfl_xor(l0, 16, 64);
    l0 += __shfl_xor(l0, 32, 64);
    float inv = 1.f / l0;

    // ---- normalize, transpose via own strip [16 q][64 hd], write AO ----
    {
      const int eswz = (l15 & 7) << 4;   // bank swizzle for 128B-stride rows
      for (int md = 0; md < 4; ++md) {
        uint2v t4 = {pkbf(o[md][0] * inv, o[md][1] * inv),
                     pkbf(o[md][2] * inv, o[md][3] * inv)};
        *(uint2v*)(Pw + l15 * 128 + ((md * 32 + quad * 8) ^ eswz)) = t4;
      }
      asm volatile("s_waitcnt lgkmcnt(0)" ::: "memory");
      int q = lane >> 2, j = lane & 3;
      size_t gbase = ((size_t)(b * S_ + t16 * 16 + q)) * D_ + h * HD_;
      for (int half = 0; half < 2; ++half) {
        bf16x8 vv = *(const bf16x8*)(Pw + q * 128 + ((half * 64 + j * 16) ^ ((q & 7) << 4)));
        *(bf16x8*)&AO[gbase + half * 32 + j * 8] = vv;
      }
    }
  }
#undef STAGE
}

// ---------------- output projection: 64x128 tiles, BK=64 ----------------
__global__ __launch_bounds__(256, 2)
void proj_gemm_kernel(const unsigned short* __restrict__ A,
                      const unsigned short* __restrict__ Bt,
                      const float* __restrict__ bias,
                      float* __restrict__ out) {
  __shared__ __align__(16) unsigned short As[2][64 * 32];
  __shared__ __align__(16) unsigned short Bs[2][128 * 32];
  const int tid = threadIdx.x;
  const int lane = tid & 63, wv = tid >> 6;
  const int quad = lane >> 4, col = lane & 15;
  const int wm = wv >> 1, wn = wv & 1;
  const int m0 = blockIdx.y * 64, n0 = blockIdx.x * 128;

  floatx4 acc[2][4] = {};

  for (int kk = 0; kk < D_; kk += 64) {
    for (int it = 0; it < 2; ++it) {     // A: 64 rows x 64 k = 512 chunks
      int c = it * 256 + tid;
      int ks = c >> 8, row = (c >> 2) & 63, kc = c & 3;
      async16(A + (size_t)(m0 + row) * D_ + kk + ks * 32 + kc * 8,
              (unsigned short*)As + c * 8);
    }
    for (int it = 0; it < 4; ++it) {     // B: 128 rows x 64 k = 1024 chunks
      int c = it * 256 + tid;
      int ks = c >> 9, row = (c >> 2) & 127, kc = c & 3;
      async16(Bt + (size_t)(n0 + row) * D_ + kk + ks * 32 + kc * 8,
              (unsigned short*)Bs + c * 8);
    }
    asm volatile("s_waitcnt vmcnt(0)" ::: "memory");
    __syncthreads();
    for (int ks = 0; ks < 2; ++ks) {
      bf16x8 af[2], bfr[4];
      for (int mt = 0; mt < 2; ++mt)
        af[mt] = *(const bf16x8*)&As[ks][(wm * 32 + mt * 16 + col) * 32 + quad * 8];
      for (int nt = 0; nt < 4; ++nt)
        bfr[nt] = *(const bf16x8*)&Bs[ks][(wn * 64 + nt * 16 + col) * 32 + quad * 8];
      for (int mt = 0; mt < 2; ++mt)
        for (int nt = 0; nt < 4; ++nt)
          acc[mt][nt] = __builtin_amdgcn_mfma_f32_16x16x32_bf16(
              af[mt], bfr[nt], acc[mt][nt], 0, 0, 0);
    }
    __syncthreads();
  }

  for (int mt = 0; mt < 2; ++mt) {
    int gm0 = m0 + wm * 32 + mt * 16 + quad * 4;
    for (int nt = 0; nt < 4; ++nt) {
      int gn = n0 + wn * 64 + nt * 16 + col;
      float bs = bias[gn];
      for (int i = 0; i < 4; ++i)
        out[(size_t)(gm0 + i) * D_ + gn] = acc[mt][nt][i] + bs;
    }
  }
}

extern "C" void kernel_launch(void* const* d_in, const int* in_sizes, int n_in,
                              void* d_out, int out_size, void* d_ws, size_t ws_size,
                              hipStream_t stream) {
  (void)in_sizes; (void)n_in; (void)out_size; (void)ws_size;
  const float* hidden = (const float*)d_in[0];
  const float* W_attn = (const float*)d_in[1];
  const float* b_attn = (const float*)d_in[2];
  const float* S_proj = (const float*)d_in[3];
  const float* W_proj = (const float*)d_in[4];
  const float* b_proj = (const float*)d_in[5];
  float* out = (float*)d_out;

  char* ws = (char*)d_ws;
  unsigned short* hB    = (unsigned short*)(ws);                    //  8 MB
  unsigned short* Bt2   = (unsigned short*)(ws + (8u << 20));       //  4 MB
  unsigned short* WpT   = (unsigned short*)(ws + (12u << 20));      //  2 MB
  float*          bias2 = (float*)         (ws + (14u << 20));      //  4 KB
  unsigned short* Qjl   = (unsigned short*)(ws + (15u << 20));      //  4 MB
  unsigned short* Kjl   = (unsigned short*)(ws + (19u << 20));      //  4 MB
  unsigned short* Vc    = (unsigned short*)(ws + (23u << 20));      //  8 MB
  unsigned short* AO    = (unsigned short*)(ws + (31u << 20));      //  8 MB

  prep_kernel<<<2688, 256, 0, stream>>>(hidden, hB, W_attn, b_attn, S_proj,
                                        W_proj, Bt2, WpT, bias2);
  qkv2_gemm_kernel<<<dim3(N2 / 128, (B_ * S_) / 128), 256, 0, stream>>>(
      hB, Bt2, b_attn, bias2, Qjl, Kjl, Vc);
  attn_kernel<<<512, 256, 0, stream>>>(Qjl, Kjl, Vc, AO);
  proj_gemm_kernel<<<dim3(D_ / 128, (B_ * S_) / 64), 256, 0, stream>>>(
      AO, WpT, b_proj, out);
}